// Round 12
// baseline (441.031 us; speedup 1.0000x reference)
//
#include <hip/hip_runtime.h>
#include <hip/hip_bf16.h>

// ---------- types ----------
typedef __attribute__((ext_vector_type(8))) short short8;   // 8 bf16 (4 VGPR)
typedef __attribute__((ext_vector_type(4))) short short4v;  // 4 bf16
typedef __attribute__((ext_vector_type(4))) float f32x4;

#define D_IN   2048
#define D_OUT  1024
#define M_ROWS 32768

__device__ __forceinline__ short f2bf(float x) {
    union { __hip_bfloat16 h; short s; } u;
    u.h = __float2bfloat16(x);
    return u.s;
}
__device__ __forceinline__ float bf2f(short s) {
    union { short s; __hip_bfloat16 h; } u;
    u.s = s;
    return __bfloat162float(u.h);
}

// ---------- 1. W [2048][1024] f32 -> Bt [1024][2048] bf16 ----------
__global__ void transpose_w_kernel(const float* __restrict__ W,
                                   short* __restrict__ Bt) {
    __shared__ float tile[32][33];
    int c0 = blockIdx.x * 32;
    int r0 = blockIdx.y * 32;
    int tc = threadIdx.x & 31;
    int tr = threadIdx.x >> 5;
#pragma unroll
    for (int i = 0; i < 32; i += 8)
        tile[tr + i][tc] = W[(long)(r0 + tr + i) * D_OUT + c0 + tc];
    __syncthreads();
#pragma unroll
    for (int i = 0; i < 32; i += 8)
        Bt[(long)(c0 + tr + i) * D_IN + r0 + tc] = f2bf(tile[tc][tr + i]);
}

// ---------- 2. GEMM 256x256 BK=64: A f32 via glds (cvt at frag-read),
//              B direct L2->reg ping-pong, ONE barrier + counted VMW per tile --
// LDS 128 KiB: A f32 only. buf p at p*65536, M-half h at h*32768 (128r x 64k f32).
// A swizzle: 256B rows = 16 atoms; phys_atom = atom ^ (row&7)  (both sides).

#define BAR()    __builtin_amdgcn_s_barrier()
#define SB0()    __builtin_amdgcn_sched_barrier(0)
#define LGKM0()  do { asm volatile("s_waitcnt lgkmcnt(0)" ::: "memory"); SB0(); } while (0)
#define VMW8()   do { asm volatile("s_waitcnt vmcnt(8)" ::: "memory"); SB0(); } while (0)

__global__ __launch_bounds__(512, 2)
void gemm256_kernel(const float* __restrict__ A,   // img f32 [32768][2048]
                    const short* __restrict__ Bt,  // [1024][2048] bf16
                    const float* __restrict__ bias, short* __restrict__ H) {
    __shared__ char LDS[131072];

    // XCD-bijective swizzle (512 % 8 == 0); bn fastest within chunk.
    int bid = blockIdx.x;
    int lid = (bid & 7) * 64 + (bid >> 3);
    int bn = lid & 3;
    int bm = lid >> 2;

    int tid  = threadIdx.x;
    int lane = tid & 63;
    int wave = tid >> 6;
    int wm = wave >> 2;            // M half
    int wn = wave & 3;             // N quarter (64 cols)
    int lrow = lane & 15;
    int lchk = lane >> 4;
    int rsw  = lrow & 7;

    const long arow0 = (long)bm * 256;
    // B per-lane base: col = bn*256 + wn*64 + nj*16 + lrow; k elems + lchk*8
    const short* bsrc = Bt + (long)(bn * 256 + wn * 64 + lrow) * D_IN + lchk * 8;

    f32x4 acc[8][4];
#pragma unroll
    for (int i = 0; i < 8; ++i)
#pragma unroll
        for (int j = 0; j < 4; ++j) acc[i][j] = (f32x4)0.0f;

// stage one 128x64 f32 A half via glds: linear dest, inverse-swizzled source
#define A_STAGE(rowbase, k0, ldsoff) do {                                       \
    _Pragma("unroll") for (int i_ = 0; i_ < 4; ++i_) {                          \
        int d_ = i_ * 8192 + tid * 16;                                          \
        int r_ = d_ >> 8;                                                       \
        int la_ = ((d_ >> 4) & 15) ^ (r_ & 7);                                  \
        __builtin_amdgcn_global_load_lds(                                       \
            (const __attribute__((address_space(1))) void*)                     \
                (A + ((rowbase) + r_) * D_IN + (k0) + la_ * 4),                 \
            (__attribute__((address_space(3))) void*)(LDS + (ldsoff) + d_),     \
            16, 0, 0);                                                          \
    }                                                                           \
} while (0)

#define B_LOADT(dst, tt) do {                                                   \
    _Pragma("unroll") for (int ks_ = 0; ks_ < 2; ++ks_)                         \
    _Pragma("unroll") for (int nj_ = 0; nj_ < 4; ++nj_)                         \
        dst[ks_][nj_] = *(const short8*)(bsrc + (long)nj_ * 16 * D_IN           \
                                         + (tt) * 64 + ks_ * 32);               \
} while (0)

// one M-quarter-pair phase: read+cvt 4 A frags per ks, 16 MFMA per ks
#define PHASE(poff, ph, B) do {                                                 \
    _Pragma("unroll") for (int ks_ = 0; ks_ < 2; ++ks_) {                       \
        short8 fa_[4];                                                          \
        _Pragma("unroll") for (int mi_ = 0; mi_ < 4; ++mi_) {                   \
            const char* pb_ = LDS + (poff) + wm * 32768                         \
                            + ((ph) * 4 + mi_) * 4096 + lrow * 256;             \
            int a0_ = ks_ * 8 + lchk * 2;                                       \
            float4 f0_ = *(const float4*)(pb_ + ((a0_ ^ rsw) << 4));            \
            float4 f1_ = *(const float4*)(pb_ + (((a0_ + 1) ^ rsw) << 4));      \
            short8 fr_;                                                         \
            fr_[0] = f2bf(f0_.x); fr_[1] = f2bf(f0_.y);                         \
            fr_[2] = f2bf(f0_.z); fr_[3] = f2bf(f0_.w);                         \
            fr_[4] = f2bf(f1_.x); fr_[5] = f2bf(f1_.y);                         \
            fr_[6] = f2bf(f1_.z); fr_[7] = f2bf(f1_.w);                         \
            fa_[mi_] = fr_;                                                     \
        }                                                                       \
        __builtin_amdgcn_s_setprio(1);                                          \
        _Pragma("unroll") for (int mi_ = 0; mi_ < 4; ++mi_)                     \
        _Pragma("unroll") for (int nj_ = 0; nj_ < 4; ++nj_)                     \
            acc[(ph) * 4 + mi_][nj_] = __builtin_amdgcn_mfma_f32_16x16x32_bf16( \
                fa_[mi_], B[ks_][nj_], acc[(ph) * 4 + mi_][nj_], 0, 0, 0);      \
        __builtin_amdgcn_s_setprio(0);                                          \
    }                                                                           \
} while (0)

    short8 bA[2][4], bB[2][4];

    // ---- prologue: A(0) -> buf0, B(0) -> regs
    A_STAGE(arow0,       0, 0);
    A_STAGE(arow0 + 128, 0, 32768);
    SB0();
    B_LOADT(bA, 0);
    SB0();
    VMW8();                        // 8 glds confirmed; 8 B-loads in flight
    BAR(); SB0();

#pragma unroll 1
    for (int t = 0; t < 32; t += 2) {
        // ---- tile t: compute from buf0/bA; stage A(t+1)->buf1, load B(t+1)
        A_STAGE(arow0,       ((t + 1) & 31) * 64, 65536);
        A_STAGE(arow0 + 128, ((t + 1) & 31) * 64, 65536 + 32768);
        SB0();
        B_LOADT(bB, t + 1);
        SB0();
        PHASE(0, 0, bA);
        PHASE(0, 1, bA);
        LGKM0();                   // all buf0 reads retired (cross-wave safety)
        VMW8();                    // A(t+1) glds done; B(t+1) stays in flight
        BAR(); SB0();              // buf1 published

        // ---- tile t+1: compute from buf1/bB; stage A(t+2)->buf0, load B(t+2)
        A_STAGE(arow0,       ((t + 2) & 31) * 64, 0);          // junk at t=30 wrap
        A_STAGE(arow0 + 128, ((t + 2) & 31) * 64, 32768);
        SB0();
        B_LOADT(bA, (t + 2) & 31);                              // junk at t=30 wrap
        SB0();
        PHASE(65536, 0, bB);
        PHASE(65536, 1, bB);
        LGKM0();
        VMW8();
        BAR(); SB0();
    }

    // ---- epilogue: + bias, ReLU, store bf16.  C/D: col=lane&15, row=(lane>>4)*4+reg
    float bb[4];
#pragma unroll
    for (int nj = 0; nj < 4; ++nj)
        bb[nj] = bias[bn * 256 + wn * 64 + nj * 16 + lrow];
#pragma unroll
    for (int mi = 0; mi < 8; ++mi) {
        long row = arow0 + wm * 128 + mi * 16 + (lane >> 4) * 4;
#pragma unroll
        for (int nj = 0; nj < 4; ++nj) {
            int col = bn * 256 + wn * 64 + nj * 16 + lrow;
#pragma unroll
            for (int r = 0; r < 4; ++r) {
                float v = fmaxf(acc[mi][nj][r] + bb[nj], 0.0f);
                H[(row + r) * D_OUT + col] = f2bf(v);
            }
        }
    }
}

// ---------- 3. LayerNorm + mask-pack (dest-indexed; writes EVERY output row) ----------
__global__ void ln_pack_kernel(const short* __restrict__ H,      // bf16 [32768][1024]
                               const int* __restrict__ mask,     // [512][64]
                               const float* __restrict__ ln_w,
                               const float* __restrict__ ln_b,
                               float* __restrict__ out) {        // [512][64][1024]
    int drow = blockIdx.x;
    int b = drow >> 6, j = drow & 63;
    int tid = threadIdx.x;
    int lane = tid & 63;
    int wave = tid >> 6;
    int base = tid * 4;

    int mv = mask[(b << 6) | lane];
    unsigned long long bal = __ballot(mv != 0);
    int cnt = __popcll(bal);

    float4 o = make_float4(0.f, 0.f, 0.f, 0.f);
    if (j < cnt) {
        int pre = __popcll(bal & ((1ull << lane) - 1ull));
        unsigned long long sel = __ballot(mv != 0 && pre == j);
        int srcn = (int)__builtin_ctzll(sel);
        long row = (long)((b << 6) | srcn);

        short4v hv = *(const short4v*)(H + row * D_OUT + base);
        float v0 = bf2f(hv[0]), v1 = bf2f(hv[1]), v2 = bf2f(hv[2]), v3 = bf2f(hv[3]);

        float s  = v0 + v1 + v2 + v3;
        float s2 = v0 * v0 + v1 * v1 + v2 * v2 + v3 * v3;
#pragma unroll
        for (int off = 32; off > 0; off >>= 1) {
            s  += __shfl_xor(s, off);
            s2 += __shfl_xor(s2, off);
        }
        __shared__ float red[8];
        if (lane == 0) { red[wave] = s; red[wave + 4] = s2; }
        __syncthreads();
        float S  = red[0] + red[1] + red[2] + red[3];
        float S2 = red[4] + red[5] + red[6] + red[7];
        float mu   = S * (1.0f / D_OUT);
        float var  = S2 * (1.0f / D_OUT) - mu * mu;
        float rstd = rsqrtf(var + 1e-12f);

        float4 wv = *(const float4*)(ln_w + base);
        float4 bv = *(const float4*)(ln_b + base);
        o.x = (v0 - mu) * rstd * wv.x + bv.x;
        o.y = (v1 - mu) * rstd * wv.y + bv.y;
        o.z = (v2 - mu) * rstd * wv.z + bv.z;
        o.w = (v3 - mu) * rstd * wv.w + bv.w;
    }
    *(float4*)(out + (long)drow * D_OUT + base) = o;
}

// ---------- launch ----------
extern "C" void kernel_launch(void* const* d_in, const int* in_sizes, int n_in,
                              void* d_out, int out_size, void* d_ws, size_t ws_size,
                              hipStream_t stream) {
    const float* img  = (const float*)d_in[0];
    const int*   mask = (const int*)d_in[2];
    const float* W    = (const float*)d_in[4];
    const float* bias = (const float*)d_in[5];
    const float* lnw  = (const float*)d_in[6];
    const float* lnb  = (const float*)d_in[7];
    float* out = (float*)d_out;

    short* Bt = (short*)d_ws;                        // 4 MiB
    short* H  = (short*)d_ws + (long)D_OUT * D_IN;   // 64 MiB

    transpose_w_kernel<<<dim3(D_OUT / 32, D_IN / 32), 256, 0, stream>>>(W, Bt);
    gemm256_kernel<<<(M_ROWS / 256) * (D_OUT / 256), 512, 0, stream>>>(img, Bt, bias, H);
    ln_pack_kernel<<<M_ROWS, 256, 0, stream>>>(H, mask, lnw, lnb, out);
}